// Round 9
// baseline (734.113 us; speedup 1.0000x reference)
//
#include <hip/hip_runtime.h>
#include <cstddef>
#include <cstring>

#define B_    2
#define L_    2048
#define DM_   1024
#define NH_   16
#define DH_   64
#define SCALE_ 0.125f   // 1/sqrt(64)

typedef __bf16 bf16x8 __attribute__((ext_vector_type(8)));
typedef float  f32x4  __attribute__((ext_vector_type(4)));
typedef unsigned short ushort8v __attribute__((ext_vector_type(8)));
typedef unsigned short ushort4v __attribute__((ext_vector_type(4)));
typedef unsigned long long u64;
typedef unsigned int u32;

__device__ __forceinline__ u32 flipf(float f) {
    u32 u = __float_as_uint(f);
    return (u & 0x80000000u) ? ~u : (u | 0x80000000u);
}
__device__ __forceinline__ float bf2f(unsigned short u) {
    return __uint_as_float(((u32)u) << 16);
}
__device__ __forceinline__ unsigned short f2bf(float f) {
    __bf16 h = (__bf16)f;
    unsigned short u;
    __builtin_memcpy(&u, &h, 2);
    return u;
}
__device__ __forceinline__ u32 flip16(unsigned short u) {
    return (u & 0x8000u) ? (u32)(~u & 0xffffu) : (u32)(u | 0x8000u);
}
__device__ __forceinline__ unsigned short unflip16(u32 k) {
    return (k & 0x8000u) ? (unsigned short)(k ^ 0x8000u) : (unsigned short)(~k & 0xffffu);
}

// ---------------------------------------------------------------------------
// Weight prep: W (K x N) fp32 -> transposed 3-level bf16 split wt1/2/3 (N x K)
// ---------------------------------------------------------------------------
__global__ __launch_bounds__(256)
void wsplit3(const float* __restrict__ W, unsigned short* __restrict__ w1,
             unsigned short* __restrict__ w2, unsigned short* __restrict__ w3,
             int K, int N) {
    const int n0 = blockIdx.x << 6;
    const int k0 = blockIdx.y << 6;
    const int t  = threadIdx.x;
    __shared__ float s[64][65];
    const int rr = t >> 4;
    const int c4 = (t & 15) << 2;
    #pragma unroll
    for (int rep = 0; rep < 4; ++rep) {
        int k = rr + (rep << 4);
        float4 x = *(const float4*)(W + (size_t)(k0 + k) * N + n0 + c4);
        s[k][c4+0] = x.x; s[k][c4+1] = x.y; s[k][c4+2] = x.z; s[k][c4+3] = x.w;
    }
    __syncthreads();
    #pragma unroll
    for (int rep = 0; rep < 4; ++rep) {
        int n = rr + (rep << 4);
        ushort4v h, m, l;
        #pragma unroll
        for (int j = 0; j < 4; ++j) {
            float x = s[c4 + j][n];
            unsigned short hh = f2bf(x);
            float r = x - bf2f(hh);
            unsigned short mm = f2bf(r);
            float r2 = r - bf2f(mm);
            h[j] = hh; m[j] = mm; l[j] = f2bf(r2);
        }
        size_t o = (size_t)(n0 + n) * K + k0 + c4;
        *(ushort4v*)(w1 + o) = h;
        *(ushort4v*)(w2 + o) = m;
        *(ushort4v*)(w3 + o) = l;
    }
}

// ---------------------------------------------------------------------------
// A-split: X (M*K fp32, contiguous) -> 3-level bf16 planes (same layout).
// ---------------------------------------------------------------------------
__global__ __launch_bounds__(256)
void asplit3(const float* __restrict__ X, unsigned short* __restrict__ p1,
             unsigned short* __restrict__ p2, unsigned short* __restrict__ p3) {
    const size_t i = ((size_t)blockIdx.x * 256 + threadIdx.x) * 8;
    float4 x0 = *(const float4*)(X + i);
    float4 x1 = *(const float4*)(X + i + 4);
    float xv[8] = {x0.x, x0.y, x0.z, x0.w, x1.x, x1.y, x1.z, x1.w};
    ushort8v h, m, l;
    #pragma unroll
    for (int e = 0; e < 8; ++e) {
        float x = xv[e];
        unsigned short hh = f2bf(x);
        float r = x - bf2f(hh);
        unsigned short mm = f2bf(r);
        h[e] = hh; m[e] = mm; l[e] = f2bf(r - bf2f(mm));
    }
    *(ushort8v*)(p1 + i) = h;
    *(ushort8v*)(p2 + i) = m;
    *(ushort8v*)(p3 + i) = l;
}

__global__ __launch_bounds__(256)
void asplit2(const float* __restrict__ X, unsigned short* __restrict__ p1,
             unsigned short* __restrict__ p2) {
    const size_t i = ((size_t)blockIdx.x * 256 + threadIdx.x) * 8;
    float4 x0 = *(const float4*)(X + i);
    float4 x1 = *(const float4*)(X + i + 4);
    float xv[8] = {x0.x, x0.y, x0.z, x0.w, x1.x, x1.y, x1.z, x1.w};
    ushort8v h, l;
    #pragma unroll
    for (int e = 0; e < 8; ++e) {
        float x = xv[e];
        unsigned short hh = f2bf(x);
        h[e] = hh; l[e] = f2bf(x - bf2f(hh));
    }
    *(ushort8v*)(p1 + i) = h;
    *(ushort8v*)(p2 + i) = l;
}

// ---------------------------------------------------------------------------
// GEMM 6-product triple-split bf16 MFMA (fp32-class): q / kv projections.
// ---------------------------------------------------------------------------
__global__ __launch_bounds__(256)
void gemm6p(const unsigned short* __restrict__ a1, const unsigned short* __restrict__ a2,
            const unsigned short* __restrict__ a3,
            const unsigned short* __restrict__ w1, const unsigned short* __restrict__ w2,
            const unsigned short* __restrict__ w3,
            float* __restrict__ C, int N, int K) {
    __shared__ __align__(16) unsigned short sA[3][128][40];
    __shared__ __align__(16) unsigned short sW[3][64][40];
    const int t    = threadIdx.x;
    const int wv   = t >> 6;
    const int lane = t & 63;
    const int quad = lane >> 4;
    const int n15  = lane & 15;
    const int bm = blockIdx.y << 7;
    const int bn = blockIdx.x << 6;
    const int wm = (wv >> 1) << 6;
    const int wn = (wv & 1) << 5;
    f32x4 acc[4][2];
    #pragma unroll
    for (int i = 0; i < 4; ++i)
        #pragma unroll
        for (int j = 0; j < 2; ++j)
            #pragma unroll
            for (int r = 0; r < 4; ++r) acc[i][j][r] = 0.f;

    const int ar  = t >> 1,  acg = (t & 1) << 4;
    const int wr  = t >> 2,  wcg = (t & 3) << 3;
    const size_t ao = (size_t)(bm + ar) * K + acg;
    const size_t wo = (size_t)(bn + wr) * K + wcg;

    for (int k0 = 0; k0 < K; k0 += 32) {
        ushort8v A1a = *(const ushort8v*)(a1 + ao + k0);
        ushort8v A1b = *(const ushort8v*)(a1 + ao + k0 + 8);
        ushort8v A2a = *(const ushort8v*)(a2 + ao + k0);
        ushort8v A2b = *(const ushort8v*)(a2 + ao + k0 + 8);
        ushort8v A3a = *(const ushort8v*)(a3 + ao + k0);
        ushort8v A3b = *(const ushort8v*)(a3 + ao + k0 + 8);
        ushort8v u1 = *(const ushort8v*)(w1 + wo + k0);
        ushort8v u2 = *(const ushort8v*)(w2 + wo + k0);
        ushort8v u3 = *(const ushort8v*)(w3 + wo + k0);
        __syncthreads();
        *(ushort8v*)&sA[0][ar][acg]     = A1a;
        *(ushort8v*)&sA[0][ar][acg + 8] = A1b;
        *(ushort8v*)&sA[1][ar][acg]     = A2a;
        *(ushort8v*)&sA[1][ar][acg + 8] = A2b;
        *(ushort8v*)&sA[2][ar][acg]     = A3a;
        *(ushort8v*)&sA[2][ar][acg + 8] = A3b;
        *(ushort8v*)&sW[0][wr][wcg] = u1;
        *(ushort8v*)&sW[1][wr][wcg] = u2;
        *(ushort8v*)&sW[2][wr][wcg] = u3;
        __syncthreads();
        bf16x8 af[3][4];
        #pragma unroll
        for (int mi = 0; mi < 4; ++mi) {
            af[0][mi] = *(const bf16x8*)&sA[0][wm + (mi << 4) + n15][quad << 3];
            af[1][mi] = *(const bf16x8*)&sA[1][wm + (mi << 4) + n15][quad << 3];
            af[2][mi] = *(const bf16x8*)&sA[2][wm + (mi << 4) + n15][quad << 3];
        }
        #pragma unroll
        for (int nj = 0; nj < 2; ++nj) {
            bf16x8 wf1 = *(const bf16x8*)&sW[0][wn + (nj << 4) + n15][quad << 3];
            bf16x8 wf2 = *(const bf16x8*)&sW[1][wn + (nj << 4) + n15][quad << 3];
            bf16x8 wf3 = *(const bf16x8*)&sW[2][wn + (nj << 4) + n15][quad << 3];
            #pragma unroll
            for (int mi = 0; mi < 4; ++mi) {
                acc[mi][nj] = __builtin_amdgcn_mfma_f32_16x16x32_bf16(af[0][mi], wf1, acc[mi][nj], 0, 0, 0);
                acc[mi][nj] = __builtin_amdgcn_mfma_f32_16x16x32_bf16(af[0][mi], wf2, acc[mi][nj], 0, 0, 0);
                acc[mi][nj] = __builtin_amdgcn_mfma_f32_16x16x32_bf16(af[1][mi], wf1, acc[mi][nj], 0, 0, 0);
                acc[mi][nj] = __builtin_amdgcn_mfma_f32_16x16x32_bf16(af[1][mi], wf2, acc[mi][nj], 0, 0, 0);
                acc[mi][nj] = __builtin_amdgcn_mfma_f32_16x16x32_bf16(af[0][mi], wf3, acc[mi][nj], 0, 0, 0);
                acc[mi][nj] = __builtin_amdgcn_mfma_f32_16x16x32_bf16(af[2][mi], wf1, acc[mi][nj], 0, 0, 0);
            }
        }
    }
    #pragma unroll
    for (int mi = 0; mi < 4; ++mi)
        #pragma unroll
        for (int nj = 0; nj < 2; ++nj)
            #pragma unroll
            for (int r = 0; r < 4; ++r)
                C[(size_t)(bm + wm + (mi << 4) + (quad << 2) + r) * N
                  + bn + wn + (nj << 4) + n15] = acc[mi][nj][r];
}

// ---------------------------------------------------------------------------
// GEMM 3-product double-split bf16 MFMA (~3e-5 abs): output projection.
// ---------------------------------------------------------------------------
__global__ __launch_bounds__(256)
void gemm3p(const unsigned short* __restrict__ a1, const unsigned short* __restrict__ a2,
            const unsigned short* __restrict__ w1, const unsigned short* __restrict__ w2,
            float* __restrict__ C, int N, int K) {
    __shared__ __align__(16) unsigned short sA[2][128][40];
    __shared__ __align__(16) unsigned short sW[2][64][40];
    const int t    = threadIdx.x;
    const int wv   = t >> 6;
    const int lane = t & 63;
    const int quad = lane >> 4;
    const int n15  = lane & 15;
    const int bm = blockIdx.y << 7;
    const int bn = blockIdx.x << 6;
    const int wm = (wv >> 1) << 6;
    const int wn = (wv & 1) << 5;
    f32x4 acc[4][2];
    #pragma unroll
    for (int i = 0; i < 4; ++i)
        #pragma unroll
        for (int j = 0; j < 2; ++j)
            #pragma unroll
            for (int r = 0; r < 4; ++r) acc[i][j][r] = 0.f;

    const int ar  = t >> 1,  acg = (t & 1) << 4;
    const int wr  = t >> 2,  wcg = (t & 3) << 3;
    const size_t ao = (size_t)(bm + ar) * K + acg;
    const size_t wo = (size_t)(bn + wr) * K + wcg;

    for (int k0 = 0; k0 < K; k0 += 32) {
        ushort8v A1a = *(const ushort8v*)(a1 + ao + k0);
        ushort8v A1b = *(const ushort8v*)(a1 + ao + k0 + 8);
        ushort8v A2a = *(const ushort8v*)(a2 + ao + k0);
        ushort8v A2b = *(const ushort8v*)(a2 + ao + k0 + 8);
        ushort8v u1 = *(const ushort8v*)(w1 + wo + k0);
        ushort8v u2 = *(const ushort8v*)(w2 + wo + k0);
        __syncthreads();
        *(ushort8v*)&sA[0][ar][acg]     = A1a;
        *(ushort8v*)&sA[0][ar][acg + 8] = A1b;
        *(ushort8v*)&sA[1][ar][acg]     = A2a;
        *(ushort8v*)&sA[1][ar][acg + 8] = A2b;
        *(ushort8v*)&sW[0][wr][wcg] = u1;
        *(ushort8v*)&sW[1][wr][wcg] = u2;
        __syncthreads();
        bf16x8 af[2][4];
        #pragma unroll
        for (int mi = 0; mi < 4; ++mi) {
            af[0][mi] = *(const bf16x8*)&sA[0][wm + (mi << 4) + n15][quad << 3];
            af[1][mi] = *(const bf16x8*)&sA[1][wm + (mi << 4) + n15][quad << 3];
        }
        #pragma unroll
        for (int nj = 0; nj < 2; ++nj) {
            bf16x8 wf1 = *(const bf16x8*)&sW[0][wn + (nj << 4) + n15][quad << 3];
            bf16x8 wf2 = *(const bf16x8*)&sW[1][wn + (nj << 4) + n15][quad << 3];
            #pragma unroll
            for (int mi = 0; mi < 4; ++mi) {
                acc[mi][nj] = __builtin_amdgcn_mfma_f32_16x16x32_bf16(af[0][mi], wf1, acc[mi][nj], 0, 0, 0);
                acc[mi][nj] = __builtin_amdgcn_mfma_f32_16x16x32_bf16(af[0][mi], wf2, acc[mi][nj], 0, 0, 0);
                acc[mi][nj] = __builtin_amdgcn_mfma_f32_16x16x32_bf16(af[1][mi], wf1, acc[mi][nj], 0, 0, 0);
            }
        }
    }
    #pragma unroll
    for (int mi = 0; mi < 4; ++mi)
        #pragma unroll
        for (int nj = 0; nj < 2; ++nj)
            #pragma unroll
            for (int r = 0; r < 4; ++r)
                C[(size_t)(bm + wm + (mi << 4) + (quad << 2) + r) * N
                  + bn + wn + (nj << 4) + n15] = acc[mi][nj][r];
}

// ---------------------------------------------------------------------------
// Column (sequence-axis) L2 norms of kv -> inv_norm[b][c]
// ---------------------------------------------------------------------------
__global__ __launch_bounds__(256)
void col_norms(const float* __restrict__ kv, float* __restrict__ invn) {
    const int bc = blockIdx.x;
    const int b  = bc >> 7;
    const int c  = bc & 127;
    const int t  = threadIdx.x;
    const float* base = kv + (size_t)b * L_ * 128 + c;
    float ss = 0.f;
    for (int l = t; l < L_; l += 256) {
        float x = base[(size_t)l * 128];
        ss += x * x;
    }
    #pragma unroll
    for (int off = 32; off; off >>= 1) ss += __shfl_xor(ss, off);
    __shared__ float red[4];
    if ((t & 63) == 0) red[t >> 6] = ss;
    __syncthreads();
    if (t == 0) {
        float tot = red[0] + red[1] + red[2] + red[3];
        invn[bc] = 1.f / fmaxf(sqrtf(tot), 1e-12f);
    }
}

// ---------------------------------------------------------------------------
// Scale kv by inv-norms: kn fp32 (b,l,64), kh bf16 (b,l,64), vT bf16 (b,64,l)
// ---------------------------------------------------------------------------
__global__ __launch_bounds__(256)
void scale_kv(const float* __restrict__ kv, const float* __restrict__ invn,
              float* __restrict__ kn, __bf16* __restrict__ kh,
              __bf16* __restrict__ vT) {
    const int b  = blockIdx.y;
    const int l0 = blockIdx.x << 6;
    const int t  = threadIdx.x;
    __shared__ float s_inv[128];
    __shared__ float s_vt[64][65];
    if (t < 128) s_inv[t] = invn[b * 128 + t];
    __syncthreads();
    #pragma unroll
    for (int rep = 0; rep < 8; ++rep) {
        int idx = (rep << 8) + t;
        int li  = idx >> 5;
        int c4  = (idx & 31) << 2;
        float4 x = *(const float4*)(kv + ((size_t)(b * L_ + l0 + li)) * 128 + c4);
        x.x *= s_inv[c4]; x.y *= s_inv[c4+1]; x.z *= s_inv[c4+2]; x.w *= s_inv[c4+3];
        if (c4 < 64) {
            size_t o = ((size_t)(b * L_ + l0 + li)) * DH_ + c4;
            *(float4*)(kn + o) = x;
            kh[o+0] = (__bf16)x.x; kh[o+1] = (__bf16)x.y;
            kh[o+2] = (__bf16)x.z; kh[o+3] = (__bf16)x.w;
        } else {
            int d = c4 - 64;
            s_vt[d+0][li] = x.x; s_vt[d+1][li] = x.y; s_vt[d+2][li] = x.z; s_vt[d+3][li] = x.w;
        }
    }
    __syncthreads();
    #pragma unroll
    for (int rep = 0; rep < 4; ++rep) {
        int idx = (rep << 8) + t;
        int d   = idx >> 4;
        int j   = (idx & 15) << 2;
        size_t o = ((size_t)b * DH_ + d) * L_ + l0 + j;
        vT[o+0] = (__bf16)s_vt[d][j+0];
        vT[o+1] = (__bf16)s_vt[d][j+1];
        vT[o+2] = (__bf16)s_vt[d][j+2];
        vT[o+3] = (__bf16)s_vt[d][j+3];
    }
}

// ---------------------------------------------------------------------------
// attn_part (R14): 4 chunks of 512 keys (was 2 halves of 1024).
// sims LDS shrinks 32KB -> 16KB; + s_prov 6KB = 22528 B total
// -> floor(163840/22528) = 7 blocks/CU (was 4). R13 showed the exact-fit
// 5-block config doesn't schedule; 7-with-slack is robust to whatever
// reserve blocked it. Serial T-phase preserved (64-VGPR class, needed
// for 7 waves/SIMD). Incremental threshold: per chunk, radix on RUNNING
// lane maxima (monotone), filter provisional list (LDS), append chunk
// passers; final chunk writes cand/candC. Final-list semantics identical
// to the 2-half scheme (elements >= full-scan threshold, 96-cap).
// ---------------------------------------------------------------------------
__global__ __launch_bounds__(256, 4)
void attn_part(const float* __restrict__ q,    // (B, L, 1024) fp32
               const __bf16* __restrict__ kh,  // (B, L, 64)  bf16
               const __bf16* __restrict__ vT,  // (B, 64, L)  bf16
               float* __restrict__ attn,       // (B, L, 1024): local part
               u32* __restrict__ cand,         // (B*NH*L, 96): (bf16bits<<16)|m
               int* __restrict__ candC) {      // (B*NH*L)
    const int tile = blockIdx.x;
    const int h    = blockIdx.y;
    const int b    = blockIdx.z;
    const int l0   = tile << 4;
    const int t    = threadIdx.x;
    const int w    = t >> 6;
    const int lane = t & 63;
    const int quad = lane >> 4;
    const int n15  = lane & 15;

    // 16384 (sims/fin union) + 6144 (prov) = 22528 B -> 7 blocks/CU
    __shared__ __align__(16) union SMem {
        unsigned short sims[16 * 512];                   // XOR-swizzled 16B units
        struct { float local[16][66]; float denom[16]; } fin;
    } sm;
    __shared__ u32 s_prov[16][96];
    unsigned short* s_sims = sm.sims;
    const int swz = n15 & 7;   // swizzle key of the sims row this thread stores/reads

    // q fragments (B-operand layout == A-operand layout)
    bf16x8 qf[2];
    {
        const float* qp = q + ((size_t)(b * L_ + l0 + n15)) * DM_ + h * DH_ + (quad << 3);
        #pragma unroll
        for (int ks = 0; ks < 2; ++ks) {
            float4 x0 = *(const float4*)(qp + (ks << 5));
            float4 x1 = *(const float4*)(qp + (ks << 5) + 4);
            float xv[8] = {x0.x, x0.y, x0.z, x0.w, x1.x, x1.y, x1.z, x1.w};
            #pragma unroll
            for (int i2 = 0; i2 < 8; ++i2) qf[ks][i2] = (__bf16)xv[i2];
        }
    }

    f32x4 accL[4] = {{0,0,0,0},{0,0,0,0},{0,0,0,0},{0,0,0,0}};
    float psum = 0.f;
    float bvmax[4] = {-3e38f, -3e38f, -3e38f, -3e38f};  // running lane maxima
    int   c0[4]    = {0, 0, 0, 0};                      // provisional counts
    const __bf16* khb = kh + (size_t)b * L_ * DH_;
    const __bf16* vtb = vT + (size_t)b * DH_ * L_;
    const int rg0 = ((b * NH_ + h) * L_) + l0;

    #pragma unroll 1
    for (int ck = 0; ck < 4; ++ck) {
        // ---- S: sims for 512-key chunk (wave w: keys [w*128, w*128+128)) ----
        #pragma unroll
        for (int g = 0; g < 2; ++g) {
            bf16x8 kf[8];
            const __bf16* kp = khb + (size_t)((ck << 9) + (w << 7) + (g << 6) + n15) * DH_ + (quad << 3);
            #pragma unroll
            for (int jj = 0; jj < 4; ++jj) {
                kf[2*jj]   = *(const bf16x8*)(kp + (size_t)(jj << 4) * DH_);
                kf[2*jj+1] = *(const bf16x8*)(kp + (size_t)(jj << 4) * DH_ + 32);
            }
            #pragma unroll
            for (int jj = 0; jj < 4; ++jj) {
                int m0 = (w << 7) + (g << 6) + (jj << 4);   // logical ushort col in chunk
                f32x4 acc = {0.f, 0.f, 0.f, 0.f};
                acc = __builtin_amdgcn_mfma_f32_16x16x32_bf16(kf[2*jj],   qf[0], acc, 0, 0, 0);
                acc = __builtin_amdgcn_mfma_f32_16x16x32_bf16(kf[2*jj+1], qf[1], acc, 0, 0, 0);
                u32 lo = (u32)f2bf(acc[0]) | ((u32)f2bf(acc[1]) << 16);
                u32 hi = (u32)f2bf(acc[2]) | ((u32)f2bf(acc[3]) << 16);
                u64 pk = ((u64)hi << 32) | lo;
                int lb = (m0 << 1) + (quad << 3);                 // logical byte in row (<1024)
                int pb = ((lb & ~15) ^ (swz << 4)) | (lb & 15);   // swizzled 16B unit
                *(u64*)((char*)s_sims + (n15 << 10) + pb) = pk;   // row stride 1024B
            }
        }
        __syncthreads();

        // ---- T: rows 4w..4w+3, serial per row; incremental threshold ----
        #pragma unroll 1
        for (int rr2 = 0; rr2 < 4; ++rr2) {
            const int r = (w << 2) + rr2;
            ushort8v rv = *(const ushort8v*)(s_sims + (r << 9) + (lane << 3));
            const int lx = (lane ^ (r & 7)) << 3;   // logical ushort base (chunk-local)
            float bv = -3e38f;
            #pragma unroll
            for (int e = 0; e < 8; ++e) bv = fmaxf(bv, bf2f(rv[e]));
            bvmax[rr2] = fmaxf(bvmax[rr2], bv);
            // radix threshold on running lane maxima (monotone nondecreasing)
            u32 key = flip16(f2bf(bvmax[rr2]));
            u32 thr = 0;
            #pragma unroll
            for (int bp = 15; bp >= 0; --bp) {
                u32 tt = thr | (1u << bp);
                if (__popcll(__ballot(key >= tt)) >= 32) thr = tt;
            }
            float thrv = bf2f(unflip16(thr)) - 0.01f;
            if (ck == 0) {
                int base = 0;
                #pragma unroll
                for (int e = 0; e < 8; ++e) {
                    bool pred = bf2f(rv[e]) >= thrv;
                    u64 mk = __ballot(pred);
                    if (pred) {
                        int pos = base + __popcll(mk & ((1ull << lane) - 1));
                        if (pos < 96)
                            s_prov[r][pos] = ((u32)rv[e] << 16) | (u32)(lx + e);
                    }
                    base += __popcll(mk);
                }
                c0[rr2] = base < 96 ? base : 96;
            } else if (ck < 3) {
                const int cc0 = c0[rr2];
                u32 e0 = (lane < cc0) ? s_prov[r][lane] : 0u;
                u32 e1 = (64 + lane < cc0) ? s_prov[r][64 + lane] : 0u;
                int base = 0;
                {   // filter existing list with tighter threshold (in-place compact)
                    bool pred = (lane < cc0)
                              && (bf2f((unsigned short)(e0 >> 16)) >= thrv);
                    u64 mk = __ballot(pred);
                    if (pred) {
                        int pos = __popcll(mk & ((1ull << lane) - 1));
                        s_prov[r][pos] = e0;
                    }
                    base = __popcll(mk);
                }
                if (cc0 > 64) {
                    bool pred = (64 + lane < cc0)
                              && (bf2f((unsigned short)(e1 >> 16)) >= thrv);
                    u64 mk = __ballot(pred);
                    if (pred) {
                        int pos = base + __popcll(mk & ((1ull << lane) - 1));
                        if (pos < 96) s_prov[r][pos] = e1;
                    }
                    base += __popcll(mk);
                }
                #pragma unroll
                for (int e = 0; e < 8; ++e) {
                    bool pred = bf2f(rv[e]) >= thrv;
                    u64 mk = __ballot(pred);
                    if (pred) {
                        int pos = base + __popcll(mk & ((1ull << lane) - 1));
                        if (pos < 96)
                            s_prov[r][pos] = ((u32)rv[e] << 16)
                                           | (u32)((ck << 9) + lx + e);
                    }
                    base += __popcll(mk);
                }
                c0[rr2] = base < 96 ? base : 96;
            } else {
                // final chunk: filter + append straight into global cand
                const int cc0 = c0[rr2];
                u32 e0 = (lane < cc0) ? s_prov[r][lane] : 0u;
                u32 e1 = (64 + lane < cc0) ? s_prov[r][64 + lane] : 0u;
                u32* cr = cand + (size_t)(rg0 + r) * 96;
                int base = 0;
                {
                    bool pred = (lane < cc0)
                              && (bf2f((unsigned short)(e0 >> 16)) >= thrv);
                    u64 mk = __ballot(pred);
                    if (pred) {
                        int pos = __popcll(mk & ((1ull << lane) - 1));
                        cr[pos] = e0;
                    }
                    base = __popcll(mk);
                }
                if (cc0 > 64) {
                    bool pred = (64 + lane < cc0)
                              && (bf2f((unsigned short)(e1 >> 16)) >= thrv);
                    u64 mk = __ballot(pred);
                    if (pred) {
                        int pos = base + __popcll(mk & ((1ull << lane) - 1));
                        if (pos < 96) cr[pos] = e1;
                    }
                    base += __popcll(mk);
                }
                #pragma unroll
                for (int e = 0; e < 8; ++e) {
                    bool pred = bf2f(rv[e]) >= thrv;
                    u64 mk = __ballot(pred);
                    if (pred) {
                        int pos = base + __popcll(mk & ((1ull << lane) - 1));
                        if (pos < 96)
                            cr[pos] = ((u32)rv[e] << 16)
                                    | (u32)((3 << 9) + lx + e);
                    }
                    base += __popcll(mk);
                }
                if (lane == 0) candC[rg0 + r] = base < 96 ? base : 96;
            }
        }

        // ---- L1: p@v for this chunk (wave w: its 128-k slab) ----
        #pragma unroll
        for (int g = 0; g < 2; ++g) {
            bf16x8 bvv[2][4];
            #pragma unroll
            for (int t2 = 0; t2 < 2; ++t2)
                #pragma unroll
                for (int nn = 0; nn < 4; ++nn)
                    bvv[t2][nn] = *(const bf16x8*)(vtb + (size_t)((nn << 4) + n15) * L_
                                  + (ck << 9) + (w << 7) + (g << 6) + (t2 << 5) + (quad << 3));
            #pragma unroll
            for (int t2 = 0; t2 < 2; ++t2) {
                int mb = (w << 7) + (g << 6) + (t2 << 5);
                int unit = (mb >> 3) + quad;                       // logical 16B unit (<64)
                ushort8v pu = *(const ushort8v*)(s_sims + (n15 << 9) + ((unit ^ swz) << 3));
                bf16x8 af;
                #pragma unroll
                for (int e = 0; e < 8; ++e) {
                    float p = __expf(SCALE_ * bf2f(pu[e]));
                    psum += p;
                    af[e] = (__bf16)p;
                }
                #pragma unroll
                for (int nn = 0; nn < 4; ++nn)
                    accL[nn] = __builtin_amdgcn_mfma_f32_16x16x32_bf16(af, bvv[t2][nn], accL[nn], 0, 0, 0);
            }
        }
        __syncthreads();   // sims consumed; next chunk may overwrite
    }

    // ---- epilogue: s_local/s_denom alias the (now dead) sims region ----
    {
        float* sl = &sm.fin.local[0][0];
        #pragma unroll 1
        for (int i = t; i < 16 * 66 + 16; i += 256) sl[i] = 0.f;  // local + denom
    }
    __syncthreads();

    psum += __shfl_xor(psum, 16);
    psum += __shfl_xor(psum, 32);
    if (lane < 16) atomicAdd(&sm.fin.denom[lane], psum);
    #pragma unroll
    for (int nn = 0; nn < 4; ++nn)
        #pragma unroll
        for (int rr = 0; rr < 4; ++rr)
            atomicAdd(&sm.fin.local[(quad << 2) + rr][(nn << 4) + n15], accL[nn][rr]);
    __syncthreads();

    // ---- write local part into attn ----
    {
        int r  = t >> 4;
        int d0 = (t & 15) << 2;
        float inv = 1.f / sm.fin.denom[r];
        float* op = attn + ((size_t)(b * L_ + l0 + r)) * DM_ + h * DH_ + d0;
        op[0] = sm.fin.local[r][d0+0] * inv;
        op[1] = sm.fin.local[r][d0+1] * inv;
        op[2] = sm.fin.local[r][d0+2] * inv;
        op[3] = sm.fin.local[r][d0+3] * inv;
    }
}

// ---------------------------------------------------------------------------
// topk_merge (R8): cooperative coalesced refine (16 lanes per candidate,
// contiguous 256B row reads), dots to LDS, then radix top-32 + retrieved.
// ---------------------------------------------------------------------------
__global__ __launch_bounds__(256)
void topk_merge(const float* __restrict__ q, const float* __restrict__ kn,
                const u32* __restrict__ cand, const int* __restrict__ candC,
                float* __restrict__ attn) {
    const int wv   = threadIdx.x >> 6;
    const int lane = threadIdx.x & 63;
    const int row  = (blockIdx.x << 2) + wv;
    const int l = row & (L_ - 1);
    const int h = (row >> 11) & (NH_ - 1);
    const int b = row >> 15;
    __shared__ float s_dot[4][96];
    __shared__ __align__(16) u64 s_sel[4][32];

    const int C = candC[row];
    const u32* cr = cand + (size_t)row * 96;
    const float* knb = kn + (size_t)b * L_ * DH_;
    const float* qr  = q + ((size_t)(b * L_ + l)) * DM_ + h * DH_;

    // preload candidate indices into registers (2 per lane covers C<=96 via shfl)
    int mreg0 = (lane < C) ? (int)(cr[lane] & 0xffffu) : 0;
    int mreg1 = (64 + lane < C) ? (int)(cr[64 + lane] & 0xffffu) : 0;

    const int cg = lane >> 4;    // candidate within pass
    const int dg = lane & 15;    // dim group (float4)
    float4 qx = *(const float4*)(qr + (dg << 2));   // fixed per lane

    #pragma unroll 2
    for (int base = 0; base < C; base += 4) {
        int ci = base + cg;
        int src = ci & 63;
        int mA = __shfl(mreg0, src);
        int mB = __shfl(mreg1, src);
        int m  = (ci < 64) ? mA : mB;
        float4 kx = *(const float4*)(knb + (size_t)m * DH_ + (dg << 2));  // coalesced 256B/group
        float p = kx.x * qx.x + kx.y * qx.y + kx.z * qx.z + kx.w * qx.w;
        p += __shfl_xor(p, 1);
        p += __shfl_xor(p, 2);
        p += __shfl_xor(p, 4);
        p += __shfl_xor(p, 8);
        if (dg == 0 && ci < C) s_dot[wv][ci] = p;
    }

    // per-lane keys from refined dots (same wave -> lgkm ordering suffices)
    float dotA = (lane < C) ? s_dot[wv][lane] : 0.f;
    float dotB = (64 + lane < C) ? s_dot[wv][64 + lane] : 0.f;
    u32 keyA = (lane < C) ? flipf(dotA) : 0u;
    u32 keyB = (64 + lane < C) ? flipf(dotB) : 0u;

    u32 thr2 = 0;
    if (C <= 64) {
        #pragma unroll
        for (int bp = 31; bp >= 0; --bp) {
            u32 tt = thr2 | (1u << bp);
            if (__popcll(__ballot(keyA >= tt)) >= 32) thr2 = tt;
        }
    } else {
        #pragma unroll
        for (int bp = 31; bp >= 0; --bp) {
            u32 tt = thr2 | (1u << bp);
            int c2 = __popcll(__ballot(keyA >= tt)) + __popcll(__ballot(keyB >= tt));
            if (c2 >= 32) thr2 = tt;
        }
    }
    {
        bool pA = keyA >= thr2;
        u64 mkA = __ballot(pA);
        if (pA) {
            int pos = __popcll(mkA & ((1ull << lane) - 1));
            if (pos < 32) {
                float pt = __expf(SCALE_ * dotA);
                s_sel[wv][pos] = ((u64)__float_as_uint(pt) << 32) | (u32)mreg0;
            }
        }
        if (C > 64) {
            int cA = __popcll(mkA);
            bool pB = keyB >= thr2;
            u64 mkB = __ballot(pB);
            if (pB) {
                int pos = cA + __popcll(mkB & ((1ull << lane) - 1));
                if (pos < 32) {
                    float pt = __expf(SCALE_ * dotB);
                    s_sel[wv][pos] = ((u64)__float_as_uint(pt) << 32) | (u32)mreg1;
                }
            }
        }
    }
    // retrieved (wave-local LDS ordering; coalesced k gathers)
    {
        float pts[32];
        int   ms[32];
        #pragma unroll
        for (int i = 0; i < 32; ++i) {
            u64 s0 = s_sel[wv][i];
            pts[i] = __uint_as_float((u32)(s0 >> 32));
            ms[i]  = (int)(u32)(s0 & 0xffffffffu);
        }
        const float* knb2 = knb + lane;
        float kvv[32];
        #pragma unroll
        for (int i = 0; i < 32; ++i) kvv[i] = knb2[(size_t)ms[i] * DH_];
        float rs = 0.f, ret = 0.f;
        #pragma unroll
        for (int i = 0; i < 16; ++i) {
            rs  += pts[2*i] + pts[2*i+1];
            ret += pts[2*i] * kvv[2*i] + pts[2*i+1] * kvv[2*i+1];
        }
        size_t oa = ((size_t)(b * L_ + l)) * DM_ + h * DH_ + lane;
        attn[oa] = attn[oa] + ret / rs;
    }
}

// ---------------------------------------------------------------------------
extern "C" void kernel_launch(void* const* d_in, const int* in_sizes, int n_in,
                              void* d_out, int out_size, void* d_ws, size_t ws_size,
                              hipStream_t stream) {
    const float* q_in     = (const float*)d_in[0];
    const float* kv_in    = (const float*)d_in[1];
    const float* w_q      = (const float*)d_in[2];
    const float* w_kv     = (const float*)d_in[3];
    const float* w_concat = (const float*)d_in[4];
    float* out = (float*)d_out;

    float* ws   = (float*)d_ws;
    float* q    = ws;                    // 4,194,304 f
    float* attn = ws + 4194304;          // 4,194,304 f
    float* kv   = attn;                  // aliased: kv dead before attn written
    float* kn   = ws + 8388608;          // 262,144 f
    float* invn = ws + 8650752;          // 256 f
    unsigned short* us = (unsigned short*)(ws + 8651008);
    unsigned short* kh_u = us;                   // 262,144
    unsigned short* vT_u = us + 262144;          // 262,144
    unsigned short* wq1  = us + 524288;          // 1,048,576 x3
    unsigned short* wq2  = wq1 + 1048576;
    unsigned short* wq3  = wq2 + 1048576;
    unsigned short* wc1  = wq3 + 1048576;        // 1,048,576 x2
    unsigned short* wc2  = wc1 + 1048576;
    unsigned short* wkv1 = wc2 + 1048576;        // 131,072 x3
    unsigned short* wkv2 = wkv1 + 131072;
    unsigned short* wkv3 = wkv2 + 131072;
    u32* cand = (u32*)(wkv3 + 131072);           // 65536*96 u32 = 25,165,824 B
    int* candC = (int*)(cand + 65536 * 96);      // 65,536 ints
    __bf16* kh = (__bf16*)kh_u;
    __bf16* vT = (__bf16*)vT_u;

    // time-shared region R1 (= cand, 25,165,824 B):
    //   phase 1: a_q planes (3x 4,194,304 ushort = exactly 25,165,824 B)
    //   phase 2: a_kv planes (same)
    //   phase 3: cand (attn_part .. topk_merge)
    //   phase 4: attn split planes (2x 4,194,304 ushort)
    unsigned short* r1 = (unsigned short*)cand;
    unsigned short* ap1 = r1;
    unsigned short* ap2 = r1 + 4194304;
    unsigned short* ap3 = r1 + 8388608;
    unsigned short* wc3 = ap1;  // wsplit3(w_concat) dummy 3rd plane (dead early)

    // weight prep
    wsplit3<<<dim3(DM_ / 64, DM_ / 64), 256, 0, stream>>>(w_q, wq1, wq2, wq3, DM_, DM_);
    wsplit3<<<dim3(DM_ / 64, DM_ / 64), 256, 0, stream>>>(w_concat, wc1, wc2, wc3, DM_, DM_);
    wsplit3<<<dim3(128 / 64, DM_ / 64), 256, 0, stream>>>(w_kv, wkv1, wkv2, wkv3, DM_, 128);

    // q projection (A pre-split once, reused by all 16 block-columns)
    asplit3<<<(B_ * L_ * DM_) / 2048, 256, 0, stream>>>(q_in, ap1, ap2, ap3);
    gemm6p<<<dim3(DM_ / 64, (B_ * L_) / 128), 256, 0, stream>>>(ap1, ap2, ap3, wq1, wq2, wq3, q, DM_, DM_);

    // kv projection (reuses R1)
    asplit3<<<(B_ * L_ * DM_) / 2048, 256, 0, stream>>>(kv_in, ap1, ap2, ap3);
    gemm6p<<<dim3(128 / 64, (B_ * L_) / 128), 256, 0, stream>>>(ap1, ap2, ap3, wkv1, wkv2, wkv3, kv, 128, DM_);

    col_norms<<<B_ * 128, 256, 0, stream>>>(kv, invn);
    scale_kv<<<dim3(L_ / 64, B_), 256, 0, stream>>>(kv, invn, kn, kh, vT);

    // attention (cand occupies R1 now; a_kv dead)
    attn_part<<<dim3(L_ / 16, NH_, B_), 256, 0, stream>>>(q, kh, vT, attn, cand, candC);
    topk_merge<<<(B_ * NH_ * L_) / 4, 256, 0, stream>>>(q, kn, cand, candC, attn);

    // output projection (attn split reuses R1; cand dead)
    asplit2<<<(B_ * L_ * DM_) / 2048, 256, 0, stream>>>(attn, ap1, ap2);
    gemm3p<<<dim3(DM_ / 64, (B_ * L_) / 128), 256, 0, stream>>>(ap1, ap2, wc1, wc2, out, DM_, DM_);
}

// Round 10
// 694.182 us; speedup vs baseline: 1.0575x; 1.0575x over previous
//
#include <hip/hip_runtime.h>
#include <cstddef>
#include <cstring>

#define B_    2
#define L_    2048
#define DM_   1024
#define NH_   16
#define DH_   64
#define SCALE_ 0.125f   // 1/sqrt(64)

typedef __bf16 bf16x8 __attribute__((ext_vector_type(8)));
typedef float  f32x4  __attribute__((ext_vector_type(4)));
typedef unsigned short ushort8v __attribute__((ext_vector_type(8)));
typedef unsigned short ushort4v __attribute__((ext_vector_type(4)));
typedef unsigned long long u64;
typedef unsigned int u32;

__device__ __forceinline__ u32 flipf(float f) {
    u32 u = __float_as_uint(f);
    return (u & 0x80000000u) ? ~u : (u | 0x80000000u);
}
__device__ __forceinline__ float bf2f(unsigned short u) {
    return __uint_as_float(((u32)u) << 16);
}
__device__ __forceinline__ unsigned short f2bf(float f) {
    __bf16 h = (__bf16)f;
    unsigned short u;
    __builtin_memcpy(&u, &h, 2);
    return u;
}
__device__ __forceinline__ u32 flip16(unsigned short u) {
    return (u & 0x8000u) ? (u32)(~u & 0xffffu) : (u32)(u | 0x8000u);
}
__device__ __forceinline__ unsigned short unflip16(u32 k) {
    return (k & 0x8000u) ? (unsigned short)(k ^ 0x8000u) : (unsigned short)(~k & 0xffffu);
}

// ---------------------------------------------------------------------------
// Weight prep: W (K x N) fp32 -> transposed 3-level bf16 split wt1/2/3 (N x K)
// ---------------------------------------------------------------------------
__global__ __launch_bounds__(256)
void wsplit3(const float* __restrict__ W, unsigned short* __restrict__ w1,
             unsigned short* __restrict__ w2, unsigned short* __restrict__ w3,
             int K, int N) {
    const int n0 = blockIdx.x << 6;
    const int k0 = blockIdx.y << 6;
    const int t  = threadIdx.x;
    __shared__ float s[64][65];
    const int rr = t >> 4;
    const int c4 = (t & 15) << 2;
    #pragma unroll
    for (int rep = 0; rep < 4; ++rep) {
        int k = rr + (rep << 4);
        float4 x = *(const float4*)(W + (size_t)(k0 + k) * N + n0 + c4);
        s[k][c4+0] = x.x; s[k][c4+1] = x.y; s[k][c4+2] = x.z; s[k][c4+3] = x.w;
    }
    __syncthreads();
    #pragma unroll
    for (int rep = 0; rep < 4; ++rep) {
        int n = rr + (rep << 4);
        ushort4v h, m, l;
        #pragma unroll
        for (int j = 0; j < 4; ++j) {
            float x = s[c4 + j][n];
            unsigned short hh = f2bf(x);
            float r = x - bf2f(hh);
            unsigned short mm = f2bf(r);
            float r2 = r - bf2f(mm);
            h[j] = hh; m[j] = mm; l[j] = f2bf(r2);
        }
        size_t o = (size_t)(n0 + n) * K + k0 + c4;
        *(ushort4v*)(w1 + o) = h;
        *(ushort4v*)(w2 + o) = m;
        *(ushort4v*)(w3 + o) = l;
    }
}

// ---------------------------------------------------------------------------
// A-split: X (M*K fp32, contiguous) -> 3-level bf16 planes (same layout).
// ---------------------------------------------------------------------------
__global__ __launch_bounds__(256)
void asplit3(const float* __restrict__ X, unsigned short* __restrict__ p1,
             unsigned short* __restrict__ p2, unsigned short* __restrict__ p3) {
    const size_t i = ((size_t)blockIdx.x * 256 + threadIdx.x) * 8;
    float4 x0 = *(const float4*)(X + i);
    float4 x1 = *(const float4*)(X + i + 4);
    float xv[8] = {x0.x, x0.y, x0.z, x0.w, x1.x, x1.y, x1.z, x1.w};
    ushort8v h, m, l;
    #pragma unroll
    for (int e = 0; e < 8; ++e) {
        float x = xv[e];
        unsigned short hh = f2bf(x);
        float r = x - bf2f(hh);
        unsigned short mm = f2bf(r);
        h[e] = hh; m[e] = mm; l[e] = f2bf(r - bf2f(mm));
    }
    *(ushort8v*)(p1 + i) = h;
    *(ushort8v*)(p2 + i) = m;
    *(ushort8v*)(p3 + i) = l;
}

__global__ __launch_bounds__(256)
void asplit2(const float* __restrict__ X, unsigned short* __restrict__ p1,
             unsigned short* __restrict__ p2) {
    const size_t i = ((size_t)blockIdx.x * 256 + threadIdx.x) * 8;
    float4 x0 = *(const float4*)(X + i);
    float4 x1 = *(const float4*)(X + i + 4);
    float xv[8] = {x0.x, x0.y, x0.z, x0.w, x1.x, x1.y, x1.z, x1.w};
    ushort8v h, l;
    #pragma unroll
    for (int e = 0; e < 8; ++e) {
        float x = xv[e];
        unsigned short hh = f2bf(x);
        h[e] = hh; l[e] = f2bf(x - bf2f(hh));
    }
    *(ushort8v*)(p1 + i) = h;
    *(ushort8v*)(p2 + i) = l;
}

// ---------------------------------------------------------------------------
// GEMM 6-product triple-split bf16 MFMA (fp32-class): q / kv projections.
// ---------------------------------------------------------------------------
__global__ __launch_bounds__(256)
void gemm6p(const unsigned short* __restrict__ a1, const unsigned short* __restrict__ a2,
            const unsigned short* __restrict__ a3,
            const unsigned short* __restrict__ w1, const unsigned short* __restrict__ w2,
            const unsigned short* __restrict__ w3,
            float* __restrict__ C, int N, int K) {
    __shared__ __align__(16) unsigned short sA[3][128][40];
    __shared__ __align__(16) unsigned short sW[3][64][40];
    const int t    = threadIdx.x;
    const int wv   = t >> 6;
    const int lane = t & 63;
    const int quad = lane >> 4;
    const int n15  = lane & 15;
    const int bm = blockIdx.y << 7;
    const int bn = blockIdx.x << 6;
    const int wm = (wv >> 1) << 6;
    const int wn = (wv & 1) << 5;
    f32x4 acc[4][2];
    #pragma unroll
    for (int i = 0; i < 4; ++i)
        #pragma unroll
        for (int j = 0; j < 2; ++j)
            #pragma unroll
            for (int r = 0; r < 4; ++r) acc[i][j][r] = 0.f;

    const int ar  = t >> 1,  acg = (t & 1) << 4;
    const int wr  = t >> 2,  wcg = (t & 3) << 3;
    const size_t ao = (size_t)(bm + ar) * K + acg;
    const size_t wo = (size_t)(bn + wr) * K + wcg;

    for (int k0 = 0; k0 < K; k0 += 32) {
        ushort8v A1a = *(const ushort8v*)(a1 + ao + k0);
        ushort8v A1b = *(const ushort8v*)(a1 + ao + k0 + 8);
        ushort8v A2a = *(const ushort8v*)(a2 + ao + k0);
        ushort8v A2b = *(const ushort8v*)(a2 + ao + k0 + 8);
        ushort8v A3a = *(const ushort8v*)(a3 + ao + k0);
        ushort8v A3b = *(const ushort8v*)(a3 + ao + k0 + 8);
        ushort8v u1 = *(const ushort8v*)(w1 + wo + k0);
        ushort8v u2 = *(const ushort8v*)(w2 + wo + k0);
        ushort8v u3 = *(const ushort8v*)(w3 + wo + k0);
        __syncthreads();
        *(ushort8v*)&sA[0][ar][acg]     = A1a;
        *(ushort8v*)&sA[0][ar][acg + 8] = A1b;
        *(ushort8v*)&sA[1][ar][acg]     = A2a;
        *(ushort8v*)&sA[1][ar][acg + 8] = A2b;
        *(ushort8v*)&sA[2][ar][acg]     = A3a;
        *(ushort8v*)&sA[2][ar][acg + 8] = A3b;
        *(ushort8v*)&sW[0][wr][wcg] = u1;
        *(ushort8v*)&sW[1][wr][wcg] = u2;
        *(ushort8v*)&sW[2][wr][wcg] = u3;
        __syncthreads();
        bf16x8 af[3][4];
        #pragma unroll
        for (int mi = 0; mi < 4; ++mi) {
            af[0][mi] = *(const bf16x8*)&sA[0][wm + (mi << 4) + n15][quad << 3];
            af[1][mi] = *(const bf16x8*)&sA[1][wm + (mi << 4) + n15][quad << 3];
            af[2][mi] = *(const bf16x8*)&sA[2][wm + (mi << 4) + n15][quad << 3];
        }
        #pragma unroll
        for (int nj = 0; nj < 2; ++nj) {
            bf16x8 wf1 = *(const bf16x8*)&sW[0][wn + (nj << 4) + n15][quad << 3];
            bf16x8 wf2 = *(const bf16x8*)&sW[1][wn + (nj << 4) + n15][quad << 3];
            bf16x8 wf3 = *(const bf16x8*)&sW[2][wn + (nj << 4) + n15][quad << 3];
            #pragma unroll
            for (int mi = 0; mi < 4; ++mi) {
                acc[mi][nj] = __builtin_amdgcn_mfma_f32_16x16x32_bf16(af[0][mi], wf1, acc[mi][nj], 0, 0, 0);
                acc[mi][nj] = __builtin_amdgcn_mfma_f32_16x16x32_bf16(af[0][mi], wf2, acc[mi][nj], 0, 0, 0);
                acc[mi][nj] = __builtin_amdgcn_mfma_f32_16x16x32_bf16(af[1][mi], wf1, acc[mi][nj], 0, 0, 0);
                acc[mi][nj] = __builtin_amdgcn_mfma_f32_16x16x32_bf16(af[1][mi], wf2, acc[mi][nj], 0, 0, 0);
                acc[mi][nj] = __builtin_amdgcn_mfma_f32_16x16x32_bf16(af[0][mi], wf3, acc[mi][nj], 0, 0, 0);
                acc[mi][nj] = __builtin_amdgcn_mfma_f32_16x16x32_bf16(af[2][mi], wf1, acc[mi][nj], 0, 0, 0);
            }
        }
    }
    #pragma unroll
    for (int mi = 0; mi < 4; ++mi)
        #pragma unroll
        for (int nj = 0; nj < 2; ++nj)
            #pragma unroll
            for (int r = 0; r < 4; ++r)
                C[(size_t)(bm + wm + (mi << 4) + (quad << 2) + r) * N
                  + bn + wn + (nj << 4) + n15] = acc[mi][nj][r];
}

// ---------------------------------------------------------------------------
// GEMM 3-product double-split bf16 MFMA (~3e-5 abs): output projection.
// ---------------------------------------------------------------------------
__global__ __launch_bounds__(256)
void gemm3p(const unsigned short* __restrict__ a1, const unsigned short* __restrict__ a2,
            const unsigned short* __restrict__ w1, const unsigned short* __restrict__ w2,
            float* __restrict__ C, int N, int K) {
    __shared__ __align__(16) unsigned short sA[2][128][40];
    __shared__ __align__(16) unsigned short sW[2][64][40];
    const int t    = threadIdx.x;
    const int wv   = t >> 6;
    const int lane = t & 63;
    const int quad = lane >> 4;
    const int n15  = lane & 15;
    const int bm = blockIdx.y << 7;
    const int bn = blockIdx.x << 6;
    const int wm = (wv >> 1) << 6;
    const int wn = (wv & 1) << 5;
    f32x4 acc[4][2];
    #pragma unroll
    for (int i = 0; i < 4; ++i)
        #pragma unroll
        for (int j = 0; j < 2; ++j)
            #pragma unroll
            for (int r = 0; r < 4; ++r) acc[i][j][r] = 0.f;

    const int ar  = t >> 1,  acg = (t & 1) << 4;
    const int wr  = t >> 2,  wcg = (t & 3) << 3;
    const size_t ao = (size_t)(bm + ar) * K + acg;
    const size_t wo = (size_t)(bn + wr) * K + wcg;

    for (int k0 = 0; k0 < K; k0 += 32) {
        ushort8v A1a = *(const ushort8v*)(a1 + ao + k0);
        ushort8v A1b = *(const ushort8v*)(a1 + ao + k0 + 8);
        ushort8v A2a = *(const ushort8v*)(a2 + ao + k0);
        ushort8v A2b = *(const ushort8v*)(a2 + ao + k0 + 8);
        ushort8v u1 = *(const ushort8v*)(w1 + wo + k0);
        ushort8v u2 = *(const ushort8v*)(w2 + wo + k0);
        __syncthreads();
        *(ushort8v*)&sA[0][ar][acg]     = A1a;
        *(ushort8v*)&sA[0][ar][acg + 8] = A1b;
        *(ushort8v*)&sA[1][ar][acg]     = A2a;
        *(ushort8v*)&sA[1][ar][acg + 8] = A2b;
        *(ushort8v*)&sW[0][wr][wcg] = u1;
        *(ushort8v*)&sW[1][wr][wcg] = u2;
        __syncthreads();
        bf16x8 af[2][4];
        #pragma unroll
        for (int mi = 0; mi < 4; ++mi) {
            af[0][mi] = *(const bf16x8*)&sA[0][wm + (mi << 4) + n15][quad << 3];
            af[1][mi] = *(const bf16x8*)&sA[1][wm + (mi << 4) + n15][quad << 3];
        }
        #pragma unroll
        for (int nj = 0; nj < 2; ++nj) {
            bf16x8 wf1 = *(const bf16x8*)&sW[0][wn + (nj << 4) + n15][quad << 3];
            bf16x8 wf2 = *(const bf16x8*)&sW[1][wn + (nj << 4) + n15][quad << 3];
            #pragma unroll
            for (int mi = 0; mi < 4; ++mi) {
                acc[mi][nj] = __builtin_amdgcn_mfma_f32_16x16x32_bf16(af[0][mi], wf1, acc[mi][nj], 0, 0, 0);
                acc[mi][nj] = __builtin_amdgcn_mfma_f32_16x16x32_bf16(af[0][mi], wf2, acc[mi][nj], 0, 0, 0);
                acc[mi][nj] = __builtin_amdgcn_mfma_f32_16x16x32_bf16(af[1][mi], wf1, acc[mi][nj], 0, 0, 0);
            }
        }
    }
    #pragma unroll
    for (int mi = 0; mi < 4; ++mi)
        #pragma unroll
        for (int nj = 0; nj < 2; ++nj)
            #pragma unroll
            for (int r = 0; r < 4; ++r)
                C[(size_t)(bm + wm + (mi << 4) + (quad << 2) + r) * N
                  + bn + wn + (nj << 4) + n15] = acc[mi][nj][r];
}

// ---------------------------------------------------------------------------
// Column (sequence-axis) L2 norms of kv -> inv_norm[b][c]
// ---------------------------------------------------------------------------
__global__ __launch_bounds__(256)
void col_norms(const float* __restrict__ kv, float* __restrict__ invn) {
    const int bc = blockIdx.x;
    const int b  = bc >> 7;
    const int c  = bc & 127;
    const int t  = threadIdx.x;
    const float* base = kv + (size_t)b * L_ * 128 + c;
    float ss = 0.f;
    for (int l = t; l < L_; l += 256) {
        float x = base[(size_t)l * 128];
        ss += x * x;
    }
    #pragma unroll
    for (int off = 32; off; off >>= 1) ss += __shfl_xor(ss, off);
    __shared__ float red[4];
    if ((t & 63) == 0) red[t >> 6] = ss;
    __syncthreads();
    if (t == 0) {
        float tot = red[0] + red[1] + red[2] + red[3];
        invn[bc] = 1.f / fmaxf(sqrtf(tot), 1e-12f);
    }
}

// ---------------------------------------------------------------------------
// Scale kv by inv-norms: kn fp32 (b,l,64), kh bf16 (b,l,64), vT bf16 (b,64,l)
// ---------------------------------------------------------------------------
__global__ __launch_bounds__(256)
void scale_kv(const float* __restrict__ kv, const float* __restrict__ invn,
              float* __restrict__ kn, __bf16* __restrict__ kh,
              __bf16* __restrict__ vT) {
    const int b  = blockIdx.y;
    const int l0 = blockIdx.x << 6;
    const int t  = threadIdx.x;
    __shared__ float s_inv[128];
    __shared__ float s_vt[64][65];
    if (t < 128) s_inv[t] = invn[b * 128 + t];
    __syncthreads();
    #pragma unroll
    for (int rep = 0; rep < 8; ++rep) {
        int idx = (rep << 8) + t;
        int li  = idx >> 5;
        int c4  = (idx & 31) << 2;
        float4 x = *(const float4*)(kv + ((size_t)(b * L_ + l0 + li)) * 128 + c4);
        x.x *= s_inv[c4]; x.y *= s_inv[c4+1]; x.z *= s_inv[c4+2]; x.w *= s_inv[c4+3];
        if (c4 < 64) {
            size_t o = ((size_t)(b * L_ + l0 + li)) * DH_ + c4;
            *(float4*)(kn + o) = x;
            kh[o+0] = (__bf16)x.x; kh[o+1] = (__bf16)x.y;
            kh[o+2] = (__bf16)x.z; kh[o+3] = (__bf16)x.w;
        } else {
            int d = c4 - 64;
            s_vt[d+0][li] = x.x; s_vt[d+1][li] = x.y; s_vt[d+2][li] = x.z; s_vt[d+3][li] = x.w;
        }
    }
    __syncthreads();
    #pragma unroll
    for (int rep = 0; rep < 4; ++rep) {
        int idx = (rep << 8) + t;
        int d   = idx >> 4;
        int j   = (idx & 15) << 2;
        size_t o = ((size_t)b * DH_ + d) * L_ + l0 + j;
        vT[o+0] = (__bf16)s_vt[d][j+0];
        vT[o+1] = (__bf16)s_vt[d][j+1];
        vT[o+2] = (__bf16)s_vt[d][j+2];
        vT[o+3] = (__bf16)s_vt[d][j+3];
    }
}

// ---------------------------------------------------------------------------
// attn_fused (R15): R12 attn_part + topk_merge fused into the epilogue.
// R14 post-mortem: occupancy is pinned at ~16 waves/CU regardless of LDS
// (37K/32K/22K all 43%), and the T-phase is only ~8% of attn_part (R14's
// +8 row-procs cost just +27us). The unmeasured ~365us/iter outside
// attn_part is the real target: fusing topk_merge deletes its launch, the
// cand/candC global round-trip (~58MB), q re-reads, and the attn RMW.
// Each wave owns its 4 rows' final list (s_prov) + count (regs): refine,
// 32-bit radix select, and retrieved run wave-locally post-L1.
// All epilogue arrays statically indexed (rule #20: no scratch).
// ---------------------------------------------------------------------------
__global__ __launch_bounds__(256, 4)
void attn_fused(const float* __restrict__ q,    // (B, L, 1024) fp32
                const __bf16* __restrict__ kh,  // (B, L, 64)  bf16
                const __bf16* __restrict__ vT,  // (B, 64, L)  bf16
                const float* __restrict__ kn,   // (B, L, 64)  fp32 normalized k
                float* __restrict__ attn) {     // (B, L, 1024): local+retrieved
    const int tile = blockIdx.x;
    const int h    = blockIdx.y;
    const int b    = blockIdx.z;
    const int l0   = tile << 4;
    const int t    = threadIdx.x;
    const int w    = t >> 6;
    const int lane = t & 63;
    const int quad = lane >> 4;
    const int n15  = lane & 15;

    // 32768 (sims/fin union) + 6144 (prov) = 38912 B -> 4 blk/CU (proven R12)
    __shared__ __align__(16) union SMem {
        unsigned short sims[16 * 1024];                  // XOR-swizzled 16B units
        struct {
            float local[16][66];      // 4224 B
            float denom[16];          //   64 B
            float dot[16][96];        // 6144 B
            float ret[16][64];        // 4096 B
            u64   sel[16][32];        // 4096 B (offset 14528, 8B-aligned)
        } fin;
    } sm;
    __shared__ u32 s_prov[16][96];
    unsigned short* s_sims = sm.sims;
    const int swz = n15 & 7;   // swizzle key of the sims row this thread stores/reads

    // q fragments (B-operand layout == A-operand layout)
    bf16x8 qf[2];
    {
        const float* qp = q + ((size_t)(b * L_ + l0 + n15)) * DM_ + h * DH_ + (quad << 3);
        #pragma unroll
        for (int ks = 0; ks < 2; ++ks) {
            float4 x0 = *(const float4*)(qp + (ks << 5));
            float4 x1 = *(const float4*)(qp + (ks << 5) + 4);
            float xv[8] = {x0.x, x0.y, x0.z, x0.w, x1.x, x1.y, x1.z, x1.w};
            #pragma unroll
            for (int i2 = 0; i2 < 8; ++i2) qf[ks][i2] = (__bf16)xv[i2];
        }
    }

    f32x4 accL[4] = {{0,0,0,0},{0,0,0,0},{0,0,0,0},{0,0,0,0}};
    float psum = 0.f;
    float bvmax[4] = {-3e38f, -3e38f, -3e38f, -3e38f};  // running full-row lane maxima
    int   c0[4]    = {0, 0, 0, 0};                      // provisional/final counts
    const __bf16* khb = kh + (size_t)b * L_ * DH_;
    const __bf16* vtb = vT + (size_t)b * DH_ * L_;
    const float*  knb = kn + (size_t)b * L_ * DH_;

    #pragma unroll 1
    for (int hf = 0; hf < 2; ++hf) {
        // ---- S: sims via swapped-operand MFMA; packed b64 swizzled stores ----
        #pragma unroll
        for (int g = 0; g < 4; ++g) {
            bf16x8 kf[8];
            const __bf16* kp = khb + (size_t)((hf << 10) + (w << 8) + (g << 6) + n15) * DH_ + (quad << 3);
            #pragma unroll
            for (int jj = 0; jj < 4; ++jj) {
                kf[2*jj]   = *(const bf16x8*)(kp + (size_t)(jj << 4) * DH_);
                kf[2*jj+1] = *(const bf16x8*)(kp + (size_t)(jj << 4) * DH_ + 32);
            }
            #pragma unroll
            for (int jj = 0; jj < 4; ++jj) {
                int m0 = (w << 8) + (g << 6) + (jj << 4);   // logical ushort col base
                f32x4 acc = {0.f, 0.f, 0.f, 0.f};
                acc = __builtin_amdgcn_mfma_f32_16x16x32_bf16(kf[2*jj],   qf[0], acc, 0, 0, 0);
                acc = __builtin_amdgcn_mfma_f32_16x16x32_bf16(kf[2*jj+1], qf[1], acc, 0, 0, 0);
                // lane holds rows m0+quad*4+{0..3} for q-row n15 -> packed store
                u32 lo = (u32)f2bf(acc[0]) | ((u32)f2bf(acc[1]) << 16);
                u32 hi = (u32)f2bf(acc[2]) | ((u32)f2bf(acc[3]) << 16);
                u64 pk = ((u64)hi << 32) | lo;
                int lb = (m0 << 1) + (quad << 3);                     // logical byte in row
                int pb = ((lb & ~15) ^ (swz << 4)) | (lb & 15);       // swizzled 16B unit
                *(u64*)((char*)s_sims + (n15 << 11) + pb) = pk;
            }
        }
        __syncthreads();

        // ---- T: rows 4w..4w+3, serial per row (R8 structure, lists in LDS) ----
        #pragma unroll 1
        for (int rr2 = 0; rr2 < 4; ++rr2) {
            const int r = (w << 2) + rr2;
            const unsigned short* srow = s_sims + (r << 10);
            ushort8v rv[2];
            rv[0] = *(const ushort8v*)(srow + (lane << 3));
            rv[1] = *(const ushort8v*)(srow + 512 + (lane << 3));
            const int lx = (lane ^ (r & 7)) << 3;   // logical ushort base of chunk
            float bv = -3e38f;
            #pragma unroll
            for (int j = 0; j < 2; ++j)
                #pragma unroll
                for (int e = 0; e < 8; ++e) bv = fmaxf(bv, bf2f(rv[j][e]));
            bvmax[rr2] = fmaxf(bvmax[rr2], bv);
            if (hf == 0) {
                // provisional half-0 threshold (16-bit radix on lane maxima)
                u32 key = flip16(f2bf(bv));
                u32 thr = 0;
                #pragma unroll
                for (int bp = 15; bp >= 0; --bp) {
                    u32 tt = thr | (1u << bp);
                    if (__popcll(__ballot(key >= tt)) >= 32) thr = tt;
                }
                float thrv = bf2f(unflip16(thr)) - 0.01f;
                int base = 0;
                #pragma unroll
                for (int j = 0; j < 2; ++j) {
                    #pragma unroll
                    for (int e = 0; e < 8; ++e) {
                        bool pred = bf2f(rv[j][e]) >= thrv;
                        u64 mk = __ballot(pred);
                        if (pred) {
                            int pos = base + __popcll(mk & ((1ull << lane) - 1));
                            if (pos < 96)
                                s_prov[r][pos] = ((u32)rv[j][e] << 16)
                                               | (u32)((j << 9) + lx + e);
                        }
                        base += __popcll(mk);
                    }
                }
                c0[rr2] = base < 96 ? base : 96;
            } else {
                // full-row threshold from running lane maxima
                u32 key = flip16(f2bf(bvmax[rr2]));
                u32 thr = 0;
                #pragma unroll
                for (int bp = 15; bp >= 0; --bp) {
                    u32 tt = thr | (1u << bp);
                    if (__popcll(__ballot(key >= tt)) >= 32) thr = tt;
                }
                float thrv = bf2f(unflip16(thr)) - 0.01f;
                const int cc0 = c0[rr2];
                u32 e0 = (lane < cc0) ? s_prov[r][lane] : 0u;
                u32 e1 = (64 + lane < cc0) ? s_prov[r][64 + lane] : 0u;
                int base = 0;
                {   // filter provisional h0 list in place with tighter threshold
                    bool pred = (lane < cc0)
                              && (bf2f((unsigned short)(e0 >> 16)) >= thrv);
                    u64 mk = __ballot(pred);
                    if (pred) {
                        int pos = __popcll(mk & ((1ull << lane) - 1));
                        s_prov[r][pos] = e0;   // pos < cc0 <= 96
                    }
                    base = __popcll(mk);
                }
                if (cc0 > 64) {
                    bool pred = (64 + lane < cc0)
                              && (bf2f((unsigned short)(e1 >> 16)) >= thrv);
                    u64 mk = __ballot(pred);
                    if (pred) {
                        int pos = base + __popcll(mk & ((1ull << lane) - 1));
                        if (pos < 96) s_prov[r][pos] = e1;
                    }
                    base += __popcll(mk);
                }
                // append half-1 candidates (ascending m preserves stable order)
                #pragma unroll
                for (int j = 0; j < 2; ++j) {
                    #pragma unroll
                    for (int e = 0; e < 8; ++e) {
                        bool pred = bf2f(rv[j][e]) >= thrv;
                        u64 mk = __ballot(pred);
                        if (pred) {
                            int pos = base + __popcll(mk & ((1ull << lane) - 1));
                            if (pos < 96)
                                s_prov[r][pos] = ((u32)rv[j][e] << 16)
                                               | (u32)(1024 + (j << 9) + lx + e);
                        }
                        base += __popcll(mk);
                    }
                }
                c0[rr2] = base < 96 ? base : 96;   // final count (in regs)
            }
        }

        // ---- L1: p@v for this half (wave w: its 256-k slab), acc in regs ----
        #pragma unroll
        for (int g = 0; g < 4; ++g) {
            bf16x8 bvv[2][4];
            #pragma unroll
            for (int t2 = 0; t2 < 2; ++t2)
                #pragma unroll
                for (int nn = 0; nn < 4; ++nn)
                    bvv[t2][nn] = *(const bf16x8*)(vtb + (size_t)((nn << 4) + n15) * L_
                                  + (hf << 10) + (w << 8) + (g << 6) + (t2 << 5) + (quad << 3));
            #pragma unroll
            for (int t2 = 0; t2 < 2; ++t2) {
                int mb = (w << 8) + (g << 6) + (t2 << 5);
                int unit = (mb >> 3) + quad;                       // logical 16B unit
                ushort8v pu = *(const ushort8v*)(s_sims + (n15 << 10) + ((unit ^ swz) << 3));
                bf16x8 af;
                #pragma unroll
                for (int e = 0; e < 8; ++e) {
                    float p = __expf(SCALE_ * bf2f(pu[e]));
                    psum += p;
                    af[e] = (__bf16)p;
                }
                #pragma unroll
                for (int nn = 0; nn < 4; ++nn)
                    accL[nn] = __builtin_amdgcn_mfma_f32_16x16x32_bf16(af, bvv[t2][nn], accL[nn], 0, 0, 0);
            }
        }
        __syncthreads();   // sims consumed; next half may overwrite
    }

    // ---- epilogue A: local-part reduction (fin overlays dead sims) ----
    {
        float* sl = &sm.fin.local[0][0];
        #pragma unroll 1
        for (int i = t; i < 16 * 66 + 16; i += 256) sl[i] = 0.f;  // local + denom
    }
    __syncthreads();

    psum += __shfl_xor(psum, 16);
    psum += __shfl_xor(psum, 32);
    if (lane < 16) atomicAdd(&sm.fin.denom[lane], psum);
    #pragma unroll
    for (int nn = 0; nn < 4; ++nn)
        #pragma unroll
        for (int rr = 0; rr < 4; ++rr)
            atomicAdd(&sm.fin.local[(quad << 2) + rr][(nn << 4) + n15], accL[nn][rr]);

    // ---- epilogue B: fused refine + top-32 select + retrieved (wave-local) ----
    {
        const int cg = lane >> 4;    // candidate within pass
        const int dg = lane & 15;    // dim group (float4)
        #pragma unroll 1
        for (int rr2 = 0; rr2 < 4; ++rr2) {
            const int r = (w << 2) + rr2;
            const int C = c0[rr2];   // >= 32 by construction
            const float* qr = q + ((size_t)(b * L_ + l0 + r)) * DM_ + h * DH_;
            float4 qx = *(const float4*)(qr + (dg << 2));
            // refine: exact fp32 dots for all C candidates (4 per pass)
            #pragma unroll 2
            for (int base = 0; base < C; base += 4) {
                int ci = base + cg;
                int m = (ci < C) ? (int)(s_prov[r][ci] & 0xffffu) : 0;
                float4 kx = *(const float4*)(knb + (size_t)m * DH_ + (dg << 2));
                float p = kx.x * qx.x + kx.y * qx.y + kx.z * qx.z + kx.w * qx.w;
                p += __shfl_xor(p, 1);
                p += __shfl_xor(p, 2);
                p += __shfl_xor(p, 4);
                p += __shfl_xor(p, 8);
                if (dg == 0 && ci < C) sm.fin.dot[r][ci] = p;
            }
            // per-lane keys (wave-local LDS ordering suffices)
            int m0r = (lane < C) ? (int)(s_prov[r][lane] & 0xffffu) : 0;
            int m1r = (64 + lane < C) ? (int)(s_prov[r][64 + lane] & 0xffffu) : 0;
            float dotA = (lane < C) ? sm.fin.dot[r][lane] : 0.f;
            float dotB = (64 + lane < C) ? sm.fin.dot[r][64 + lane] : 0.f;
            u32 keyA = (lane < C) ? flipf(dotA) : 0u;
            u32 keyB = (64 + lane < C) ? flipf(dotB) : 0u;
            u32 thr2 = 0;
            if (C <= 64) {
                #pragma unroll
                for (int bp = 31; bp >= 0; --bp) {
                    u32 tt = thr2 | (1u << bp);
                    if (__popcll(__ballot(keyA >= tt)) >= 32) thr2 = tt;
                }
            } else {
                #pragma unroll
                for (int bp = 31; bp >= 0; --bp) {
                    u32 tt = thr2 | (1u << bp);
                    int c2 = __popcll(__ballot(keyA >= tt)) + __popcll(__ballot(keyB >= tt));
                    if (c2 >= 32) thr2 = tt;
                }
            }
            {
                bool pA = keyA >= thr2;
                u64 mkA = __ballot(pA);
                if (pA) {
                    int pos = __popcll(mkA & ((1ull << lane) - 1));
                    if (pos < 32) {
                        float pt = __expf(SCALE_ * dotA);
                        sm.fin.sel[r][pos] = ((u64)__float_as_uint(pt) << 32) | (u32)m0r;
                    }
                }
                if (C > 64) {
                    int cA = __popcll(mkA);
                    bool pB = keyB >= thr2;
                    u64 mkB = __ballot(pB);
                    if (pB) {
                        int pos = cA + __popcll(mkB & ((1ull << lane) - 1));
                        if (pos < 32) {
                            float pt = __expf(SCALE_ * dotB);
                            sm.fin.sel[r][pos] = ((u64)__float_as_uint(pt) << 32) | (u32)m1r;
                        }
                    }
                }
            }
            // retrieved: two 16-chunks (keeps live arrays small, static idx)
            float rs = 0.f, ret = 0.f;
            const float* knl = knb + lane;
            #pragma unroll
            for (int c2 = 0; c2 < 2; ++c2) {
                float pts[16]; int ms[16]; float kvv[16];
                #pragma unroll
                for (int i = 0; i < 16; ++i) {
                    u64 s0 = sm.fin.sel[r][(c2 << 4) + i];
                    pts[i] = __uint_as_float((u32)(s0 >> 32));
                    ms[i]  = (int)(u32)(s0 & 0xffffffffu);
                }
                #pragma unroll
                for (int i = 0; i < 16; ++i) kvv[i] = knl[(size_t)ms[i] * DH_];
                #pragma unroll
                for (int i = 0; i < 16; ++i) { rs += pts[i]; ret += pts[i] * kvv[i]; }
            }
            sm.fin.ret[r][lane] = ret / rs;
        }
    }
    __syncthreads();

    // ---- final write: local/denom + retrieved in one pass ----
    {
        int r  = t >> 4;
        int d0 = (t & 15) << 2;
        float inv = 1.f / sm.fin.denom[r];
        float* op = attn + ((size_t)(b * L_ + l0 + r)) * DM_ + h * DH_ + d0;
        op[0] = sm.fin.local[r][d0+0] * inv + sm.fin.ret[r][d0+0];
        op[1] = sm.fin.local[r][d0+1] * inv + sm.fin.ret[r][d0+1];
        op[2] = sm.fin.local[r][d0+2] * inv + sm.fin.ret[r][d0+2];
        op[3] = sm.fin.local[r][d0+3] * inv + sm.fin.ret[r][d0+3];
    }
}

// ---------------------------------------------------------------------------
extern "C" void kernel_launch(void* const* d_in, const int* in_sizes, int n_in,
                              void* d_out, int out_size, void* d_ws, size_t ws_size,
                              hipStream_t stream) {
    const float* q_in     = (const float*)d_in[0];
    const float* kv_in    = (const float*)d_in[1];
    const float* w_q      = (const float*)d_in[2];
    const float* w_kv     = (const float*)d_in[3];
    const float* w_concat = (const float*)d_in[4];
    float* out = (float*)d_out;

    float* ws   = (float*)d_ws;
    float* q    = ws;                    // 4,194,304 f
    float* attn = ws + 4194304;          // 4,194,304 f
    float* kv   = attn;                  // aliased: kv dead before attn written
    float* kn   = ws + 8388608;          // 262,144 f
    float* invn = ws + 8650752;          // 256 f
    unsigned short* us = (unsigned short*)(ws + 8651008);
    unsigned short* kh_u = us;                   // 262,144
    unsigned short* vT_u = us + 262144;          // 262,144
    unsigned short* wq1  = us + 524288;          // 1,048,576 x3
    unsigned short* wq2  = wq1 + 1048576;
    unsigned short* wq3  = wq2 + 1048576;
    unsigned short* wc1  = wq3 + 1048576;        // 1,048,576 x2
    unsigned short* wc2  = wc1 + 1048576;
    unsigned short* wkv1 = wc2 + 1048576;        // 131,072 x3
    unsigned short* wkv2 = wkv1 + 131072;
    unsigned short* wkv3 = wkv2 + 131072;
    __bf16* kh = (__bf16*)kh_u;
    __bf16* vT = (__bf16*)vT_u;

    // time-shared region R1 (25,165,824 B, after wkv3):
    //   phase 1: a_q planes (3x 4,194,304 ushort)
    //   phase 2: a_kv planes (same)
    //   phase 3: (idle during fused attention)
    //   phase 4: attn split planes (2x 4,194,304 ushort)
    unsigned short* r1 = wkv3 + 131072;
    unsigned short* ap1 = r1;
    unsigned short* ap2 = r1 + 4194304;
    unsigned short* ap3 = r1 + 8388608;
    unsigned short* wc3 = ap1;  // wsplit3(w_concat) dummy 3rd plane (dead early)

    // weight prep
    wsplit3<<<dim3(DM_ / 64, DM_ / 64), 256, 0, stream>>>(w_q, wq1, wq2, wq3, DM_, DM_);
    wsplit3<<<dim3(DM_ / 64, DM_ / 64), 256, 0, stream>>>(w_concat, wc1, wc2, wc3, DM_, DM_);
    wsplit3<<<dim3(128 / 64, DM_ / 64), 256, 0, stream>>>(w_kv, wkv1, wkv2, wkv3, DM_, 128);

    // q projection (A pre-split once, reused by all 16 block-columns)
    asplit3<<<(B_ * L_ * DM_) / 2048, 256, 0, stream>>>(q_in, ap1, ap2, ap3);
    gemm6p<<<dim3(DM_ / 64, (B_ * L_) / 128), 256, 0, stream>>>(ap1, ap2, ap3, wq1, wq2, wq3, q, DM_, DM_);

    // kv projection (reuses R1)
    asplit3<<<(B_ * L_ * DM_) / 2048, 256, 0, stream>>>(kv_in, ap1, ap2, ap3);
    gemm6p<<<dim3(128 / 64, (B_ * L_) / 128), 256, 0, stream>>>(ap1, ap2, ap3, wkv1, wkv2, wkv3, kv, 128, DM_);

    col_norms<<<B_ * 128, 256, 0, stream>>>(kv, invn);
    scale_kv<<<dim3(L_ / 64, B_), 256, 0, stream>>>(kv, invn, kn, kh, vT);

    // fused attention (local + topk refine/select/retrieved in one kernel)
    attn_fused<<<dim3(L_ / 16, NH_, B_), 256, 0, stream>>>(q, kh, vT, kn, attn);

    // output projection (attn split reuses R1)
    asplit2<<<(B_ * L_ * DM_) / 2048, 256, 0, stream>>>(attn, ap1, ap2);
    gemm3p<<<dim3(DM_ / 64, (B_ * L_) / 128), 256, 0, stream>>>(ap1, ap2, wc1, wc2, out, DM_, DM_);
}